// Round 3
// baseline (1215.805 us; speedup 1.0000x reference)
//
#include <hip/hip_runtime.h>
#include <math.h>

#define D_MODEL 1024
#define N_HEADS 16
#define D_K     64
#define SEQ     2048
#define BATCH   4
#define EPS     1e-5f

typedef __attribute__((ext_vector_type(8))) short bf16x8;
typedef __attribute__((ext_vector_type(4))) float f32x4;

__device__ __forceinline__ unsigned short f2bf(float f) {
    unsigned u = __float_as_uint(f);
    u += 0x7fff + ((u >> 16) & 1);   // RNE
    return (unsigned short)(u >> 16);
}

#define GLDS16(g, l) __builtin_amdgcn_global_load_lds( \
    (const __attribute__((address_space(1))) void*)(g), \
    (__attribute__((address_space(3))) void*)(l), 16, 0, 0)

// ---------------------------------------------------------------------------
// f32 -> bf16 bulk convert (4 elems/thread)
// ---------------------------------------------------------------------------
__global__ __launch_bounds__(256) void cvt_f32_bf16(
    const float* __restrict__ in, unsigned short* __restrict__ out, int n4)
{
    int i = blockIdx.x * 256 + threadIdx.x;
    if (i >= n4) return;
    float4 f = ((const float4*)in)[i];
    union { ushort4 u; uint2 v; } o;
    o.u.x = f2bf(f.x); o.u.y = f2bf(f.y); o.u.z = f2bf(f.z); o.u.w = f2bf(f.w);
    ((uint2*)out)[i] = o.v;
}

// ---------------------------------------------------------------------------
// Fused QKV projection: for t in {q,k,v}: Ot = x @ Wt^T + bt  (bf16 out)
// Q additionally scaled by 0.125 (folded 1/sqrt(d_k)).
// grid.x = 24 : [which 0..2][bn 0..7] ; grid.y = 64 row tiles. 128x128, BK=32.
// ---------------------------------------------------------------------------
__global__ __launch_bounds__(256) void gemm_qkv(
    const unsigned short* __restrict__ A,
    const unsigned short* __restrict__ Bq, const unsigned short* __restrict__ Bk,
    const unsigned short* __restrict__ Bv,
    const float* __restrict__ biq, const float* __restrict__ bik,
    const float* __restrict__ biv,
    unsigned short* __restrict__ Oq, unsigned short* __restrict__ Ok,
    unsigned short* __restrict__ Ov)
{
    const int which = blockIdx.x >> 3;
    const unsigned short* B = which == 0 ? Bq : (which == 1 ? Bk : Bv);
    const float* bias        = which == 0 ? biq : (which == 1 ? bik : biv);
    unsigned short* O        = which == 0 ? Oq : (which == 1 ? Ok : Ov);
    const float scale        = which == 0 ? 0.125f : 1.0f;

    __shared__ unsigned short As[128 * 32];
    __shared__ unsigned short Bs[128 * 32];
    const int tid = threadIdx.x;
    const int w = tid >> 6, lane = tid & 63;
    const int l15 = lane & 15, lh = lane >> 4;
    const int wm = w >> 1, wn = w & 1;
    const int bm = blockIdx.y * 128, bn = (blockIdx.x & 7) * 128;
    const int K = D_MODEL, N = D_MODEL;

    const int srow = lane >> 2;
    const int skk  = (lane & 3) * 8;

    f32x4 acc[4][4] = {};

    for (int k0 = 0; k0 < K; k0 += 32) {
#pragma unroll
        for (int cc = 0; cc < 2; ++cc) {
            int chunk = w * 2 + cc;
            int row = chunk * 16 + srow;
            GLDS16(A + (size_t)(bm + row) * K + k0 + skk, As + chunk * 512);
            GLDS16(B + (size_t)(bn + row) * K + k0 + skk, Bs + chunk * 512);
        }
        __syncthreads();
        bf16x8 af[4], bfr[4];
#pragma unroll
        for (int mi = 0; mi < 4; ++mi)
            af[mi] = *(const bf16x8*)&As[(wm * 64 + mi * 16 + l15) * 32 + lh * 8];
#pragma unroll
        for (int nj = 0; nj < 4; ++nj)
            bfr[nj] = *(const bf16x8*)&Bs[(wn * 64 + nj * 16 + l15) * 32 + lh * 8];
#pragma unroll
        for (int mi = 0; mi < 4; ++mi)
#pragma unroll
            for (int nj = 0; nj < 4; ++nj)
                acc[mi][nj] = __builtin_amdgcn_mfma_f32_16x16x32_bf16(
                    af[mi], bfr[nj], acc[mi][nj], 0, 0, 0);
        __syncthreads();
    }

#pragma unroll
    for (int mi = 0; mi < 4; ++mi) {
#pragma unroll
        for (int nj = 0; nj < 4; ++nj) {
            int col = bn + wn * 64 + nj * 16 + l15;
            float bv = bias[col];
#pragma unroll
            for (int r = 0; r < 4; ++r) {
                int row = bm + wm * 64 + mi * 16 + lh * 4 + r;
                O[(size_t)row * N + col] = f2bf((acc[mi][nj][r] + bv) * scale);
            }
        }
    }
}

// ---------------------------------------------------------------------------
// Output projection: C = ctx @ Wo^T + bo + residual (fp32 out). 128x128, BK=32.
// ---------------------------------------------------------------------------
__global__ __launch_bounds__(256) void gemm_out(
    const unsigned short* __restrict__ A, const unsigned short* __restrict__ B,
    const float* __restrict__ bias, const float* __restrict__ res,
    float* __restrict__ C)
{
    __shared__ unsigned short As[128 * 32];
    __shared__ unsigned short Bs[128 * 32];
    const int tid = threadIdx.x;
    const int w = tid >> 6, lane = tid & 63;
    const int l15 = lane & 15, lh = lane >> 4;
    const int wm = w >> 1, wn = w & 1;
    const int bm = blockIdx.y * 128, bn = blockIdx.x * 128;
    const int K = D_MODEL, N = D_MODEL;

    const int srow = lane >> 2;
    const int skk  = (lane & 3) * 8;

    f32x4 acc[4][4] = {};

    for (int k0 = 0; k0 < K; k0 += 32) {
#pragma unroll
        for (int cc = 0; cc < 2; ++cc) {
            int chunk = w * 2 + cc;
            int row = chunk * 16 + srow;
            GLDS16(A + (size_t)(bm + row) * K + k0 + skk, As + chunk * 512);
            GLDS16(B + (size_t)(bn + row) * K + k0 + skk, Bs + chunk * 512);
        }
        __syncthreads();
        bf16x8 af[4], bfr[4];
#pragma unroll
        for (int mi = 0; mi < 4; ++mi)
            af[mi] = *(const bf16x8*)&As[(wm * 64 + mi * 16 + l15) * 32 + lh * 8];
#pragma unroll
        for (int nj = 0; nj < 4; ++nj)
            bfr[nj] = *(const bf16x8*)&Bs[(wn * 64 + nj * 16 + l15) * 32 + lh * 8];
#pragma unroll
        for (int mi = 0; mi < 4; ++mi)
#pragma unroll
            for (int nj = 0; nj < 4; ++nj)
                acc[mi][nj] = __builtin_amdgcn_mfma_f32_16x16x32_bf16(
                    af[mi], bfr[nj], acc[mi][nj], 0, 0, 0);
        __syncthreads();
    }

#pragma unroll
    for (int mi = 0; mi < 4; ++mi) {
#pragma unroll
        for (int nj = 0; nj < 4; ++nj) {
            int col = bn + wn * 64 + nj * 16 + l15;
            float bv = bias[col];
#pragma unroll
            for (int r = 0; r < 4; ++r) {
                int row = bm + wm * 64 + mi * 16 + lh * 4 + r;
                C[(size_t)row * N + col] = acc[mi][nj][r] + bv + res[(size_t)row * N + col];
            }
        }
    }
}

// ---------------------------------------------------------------------------
// Single-pass fused attention. QBLK=16 q-rows/block, 4 waves, KVBLK=64.
// QK^T computed once; exp(s) (unnormalized, |s| small -> safe) kept as bf16 in
// LDS Ps[16][2048]; PV accumulated online with unnormalized P; row sums in
// registers. Epilogue: O *= 1/l -> ctx (bf16); P normalized LDS->global fp32.
// LDS = 64K (Ps, XOR-swizzled) + 8K (Kt) + 8K (Vt transposed) = 80 KB
//  -> 2 blocks/CU so one block's P-write overlaps the other's compute.
// ---------------------------------------------------------------------------
__global__ __launch_bounds__(256) void attn_onepass(
    const unsigned short* __restrict__ qb, const unsigned short* __restrict__ kb,
    const unsigned short* __restrict__ vb,
    float* __restrict__ attnP, unsigned short* __restrict__ ctx)
{
    __shared__ unsigned short Ps[16 * 2048];   // byte ^= (row&7)<<4
    __shared__ unsigned short Kt[64 * 64];     // [key][d], chunk ^= key&7
    __shared__ unsigned short Vt[64 * 64];     // [d][key] transposed, chunk ^= d&7

    const int bh = blockIdx.y, b = bh >> 4, head = bh & 15;
    const int bq = blockIdx.x * 16;
    const int tid = threadIdx.x;
    const int w = tid >> 6, lane = tid & 63, l15 = lane & 15, lh = lane >> 4;
    const size_t rowbase = (size_t)b * SEQ;

    // Q fragments: lane l15 = qrow (B-operand col), lh*8 = d-offset
    bf16x8 aq[2];
#pragma unroll
    for (int kd = 0; kd < 2; ++kd)
        aq[kd] = *(const bf16x8*)(qb + (rowbase + bq + l15) * D_MODEL + head * 64 + kd * 32 + lh * 8);

    float rsum = 0.f;
    f32x4 ot = {};

    uint4 kreg[2], vreg[2];
#pragma unroll
    for (int i = 0; i < 2; ++i) {
        int c = tid + i * 256, key = c >> 3, cc = c & 7;
        kreg[i] = *(const uint4*)(kb + (rowbase + key) * D_MODEL + head * 64 + cc * 8);
        vreg[i] = *(const uint4*)(vb + (rowbase + key) * D_MODEL + head * 64 + cc * 8);
    }

    for (int kt = 0; kt < SEQ / 64; ++kt) {
        __syncthreads();                        // prev PV done with Kt/Vt
#pragma unroll
        for (int i = 0; i < 2; ++i) {
            int c = tid + i * 256, key = c >> 3, cc = c & 7;
            int ccs = cc ^ (key & 7);
            *(uint4*)((char*)Kt + key * 128 + ccs * 16) = kreg[i];
            const unsigned short* pv = (const unsigned short*)&vreg[i];
#pragma unroll
            for (int e = 0; e < 8; ++e) {
                int d = cc * 8 + e;
                int kc = (key >> 3) ^ (d & 7);
                Vt[d * 64 + kc * 8 + (key & 7)] = pv[e];
            }
        }
        __syncthreads();                        // staged tile visible
        if (kt + 1 < SEQ / 64) {                // async-split: issue next loads now
            int bk1 = (kt + 1) * 64;
#pragma unroll
            for (int i = 0; i < 2; ++i) {
                int c = tid + i * 256, key = c >> 3, cc = c & 7;
                kreg[i] = *(const uint4*)(kb + (rowbase + bk1 + key) * D_MODEL + head * 64 + cc * 8);
                vreg[i] = *(const uint4*)(vb + (rowbase + bk1 + key) * D_MODEL + head * 64 + cc * 8);
            }
        }

        // QK^T (swapped): S^T[key][q]; wave w owns keys w*16..+15
        f32x4 s = {};
#pragma unroll
        for (int kd = 0; kd < 2; ++kd) {
            int key = w * 16 + l15;
            int cc = (kd * 4 + lh) ^ (key & 7);
            bf16x8 kf = *(const bf16x8*)((const char*)Kt + key * 128 + cc * 16);
            s = __builtin_amdgcn_mfma_f32_16x16x32_bf16(kf, aq[kd], s, 0, 0, 0);
        }
        // exp + row-sum (lane holds keys w*16+lh*4..+3 for qrow l15)
        float p0 = __expf(s[0]), p1 = __expf(s[1]);
        float p2 = __expf(s[2]), p3 = __expf(s[3]);
        float psum = (p0 + p1) + (p2 + p3);
        psum += __shfl_xor(psum, 16);
        psum += __shfl_xor(psum, 32);
        rsum += psum;
        uint2 pk;
        pk.x = ((unsigned)f2bf(p1) << 16) | f2bf(p0);
        pk.y = ((unsigned)f2bf(p3) << 16) | f2bf(p2);
        {
            int keyb = kt * 64 + w * 16 + lh * 4;
            unsigned bo = (unsigned)(l15 * 4096 + keyb * 2) ^ ((unsigned)(l15 & 7) << 4);
            *(uint2*)((char*)Ps + bo) = pk;
        }
        __syncthreads();                        // Ps slice visible to all waves

        // PV online: wave w owns d-block w*16..+15 ; O^T[d][q]
#pragma unroll
        for (int ks = 0; ks < 2; ++ks) {
            unsigned pbo = (unsigned)(l15 * 4096 + (kt * 64 + ks * 32 + lh * 8) * 2)
                           ^ ((unsigned)(l15 & 7) << 4);
            bf16x8 pb = *(const bf16x8*)((const char*)Ps + pbo);
            int d = w * 16 + l15;
            int kc = (ks * 4 + lh) ^ (d & 7);
            bf16x8 va = *(const bf16x8*)((const char*)Vt + d * 128 + kc * 16);
            ot = __builtin_amdgcn_mfma_f32_16x16x32_bf16(va, pb, ot, 0, 0, 0);
        }
    }
    __syncthreads();                            // loop done; Kt reusable

    // cross-wave row-sum reduce (each wave covered keys with (key>>4)&3 == w)
    float* redf = (float*)Kt;
    if (lane < 16) redf[w * 16 + lane] = rsum;
    __syncthreads();

    // O write: col = qrow = l15, row d = w*16 + lh*4 + r
    {
        float invl = 1.0f / (redf[l15] + redf[16 + l15] + redf[32 + l15] + redf[48 + l15]);
        union { ushort4 u; uint2 v; } o;
        o.u.x = f2bf(ot[0] * invl); o.u.y = f2bf(ot[1] * invl);
        o.u.z = f2bf(ot[2] * invl); o.u.w = f2bf(ot[3] * invl);
        *(uint2*)&ctx[(rowbase + bq + l15) * D_MODEL + head * 64 + w * 16 + lh * 4] = o.v;
    }

    // P write: normalize LDS -> global fp32. thread: row = tid>>4, seg = tid&15
    {
        int row = tid >> 4, seg = tid & 15;
        float invr = 1.0f / (redf[row] + redf[16 + row] + redf[32 + row] + redf[48 + row]);
        float* dst = attnP + ((size_t)bh * SEQ + bq + row) * SEQ;
        unsigned swz = (unsigned)((row & 7) << 4);
#pragma unroll
        for (int j = 0; j < 8; ++j) {
            int key = j * 256 + seg * 16;
            unsigned base = (unsigned)(row * 4096 + key * 2);
            uint4 a0 = *(const uint4*)((const char*)Ps + (base ^ swz));
            uint4 a1 = *(const uint4*)((const char*)Ps + ((base + 16) ^ swz));
            const unsigned* ua = (const unsigned*)&a0;
            const unsigned* ub = (const unsigned*)&a1;
            float f[16];
#pragma unroll
            for (int q2 = 0; q2 < 4; ++q2) {
                f[2 * q2]         = __uint_as_float(ua[q2] << 16) * invr;
                f[2 * q2 + 1]     = __uint_as_float(ua[q2] & 0xffff0000u) * invr;
                f[8 + 2 * q2]     = __uint_as_float(ub[q2] << 16) * invr;
                f[8 + 2 * q2 + 1] = __uint_as_float(ub[q2] & 0xffff0000u) * invr;
            }
#pragma unroll
            for (int q4 = 0; q4 < 4; ++q4)
                *(float4*)(dst + key + q4 * 4) = *(float4*)&f[q4 * 4];
        }
    }
}

// ---------------------------------------------------------------------------
// LayerNorm over last dim (1024). 1 block/row.
// ---------------------------------------------------------------------------
__global__ __launch_bounds__(256) void layernorm_rows(
    const float* __restrict__ h, const float* __restrict__ gamma,
    const float* __restrict__ beta, float* __restrict__ out)
{
    const size_t row = blockIdx.x;
    const float* hr = h + row * D_MODEL;
    const int tid = threadIdx.x;

    float v[4];
    float s = 0.f;
#pragma unroll
    for (int i = 0; i < 4; ++i) { v[i] = hr[tid + i * 256]; s += v[i]; }
    __shared__ float red[256];
    red[tid] = s;
    __syncthreads();
    for (int st = 128; st > 0; st >>= 1) {
        if (tid < st) red[tid] += red[tid + st];
        __syncthreads();
    }
    float mean = red[0] * (1.0f / D_MODEL);
    __syncthreads();

    float vs = 0.f;
#pragma unroll
    for (int i = 0; i < 4; ++i) { float d = v[i] - mean; vs += d * d; }
    red[tid] = vs;
    __syncthreads();
    for (int st = 128; st > 0; st >>= 1) {
        if (tid < st) red[tid] += red[tid + st];
        __syncthreads();
    }
    float inv = rsqrtf(red[0] * (1.0f / D_MODEL) + EPS);

#pragma unroll
    for (int i = 0; i < 4; ++i) {
        int c = tid + i * 256;
        out[row * D_MODEL + c] = (v[i] - mean) * inv * gamma[c] + beta[c];
    }
}

// ---------------------------------------------------------------------------
extern "C" void kernel_launch(void* const* d_in, const int* in_sizes, int n_in,
                              void* d_out, int out_size, void* d_ws, size_t ws_size,
                              hipStream_t stream)
{
    const float* x     = (const float*)d_in[0];
    const float* Wq    = (const float*)d_in[1];
    const float* bq_   = (const float*)d_in[2];
    const float* Wk    = (const float*)d_in[3];
    const float* bk_   = (const float*)d_in[4];
    const float* Wv    = (const float*)d_in[5];
    const float* bv_   = (const float*)d_in[6];
    const float* Wo    = (const float*)d_in[7];
    const float* bo_   = (const float*)d_in[8];
    const float* gamma = (const float*)d_in[9];
    const float* beta  = (const float*)d_in[10];

    const size_t NX = (size_t)BATCH * SEQ * D_MODEL;   // 8388608
    const size_t NW = (size_t)D_MODEL * D_MODEL;       // 1048576

    float* out_ln = (float*)d_out;
    float* attnP  = out_ln + NX;

    unsigned short* x_bf   = (unsigned short*)d_ws;
    unsigned short* wq_bf  = x_bf + NX;
    unsigned short* wk_bf  = wq_bf + NW;
    unsigned short* wv_bf  = wk_bf + NW;
    unsigned short* wo_bf  = wv_bf + NW;
    unsigned short* q_bf   = wo_bf + NW;
    unsigned short* k_bf   = q_bf + NX;
    unsigned short* v_bf   = k_bf + NX;
    unsigned short* ctx_bf = v_bf + NX;
    float* hbuf = (float*)(ctx_bf + NX);

    const int M = BATCH * SEQ;   // 8192

    cvt_f32_bf16<<<(int)(NX / 4 / 256), 256, 0, stream>>>(x, x_bf, (int)(NX / 4));
    cvt_f32_bf16<<<(int)(NW / 4 / 256), 256, 0, stream>>>(Wq, wq_bf, (int)(NW / 4));
    cvt_f32_bf16<<<(int)(NW / 4 / 256), 256, 0, stream>>>(Wk, wk_bf, (int)(NW / 4));
    cvt_f32_bf16<<<(int)(NW / 4 / 256), 256, 0, stream>>>(Wv, wv_bf, (int)(NW / 4));
    cvt_f32_bf16<<<(int)(NW / 4 / 256), 256, 0, stream>>>(Wo, wo_bf, (int)(NW / 4));

    gemm_qkv<<<dim3(24, M / 128), 256, 0, stream>>>(
        x_bf, wq_bf, wk_bf, wv_bf, bq_, bk_, bv_, q_bf, k_bf, v_bf);

    attn_onepass<<<dim3(SEQ / 16, BATCH * N_HEADS), 256, 0, stream>>>(
        q_bf, k_bf, v_bf, attnP, ctx_bf);

    gemm_out<<<dim3(D_MODEL / 128, M / 128), 256, 0, stream>>>(
        ctx_bf, wo_bf, bo_, x, hbuf);

    layernorm_rows<<<M, 256, 0, stream>>>(hbuf, gamma, beta, out_ln);
}

// Round 4
// 840.829 us; speedup vs baseline: 1.4460x; 1.4460x over previous
//
#include <hip/hip_runtime.h>
#include <math.h>

#define D_MODEL 1024
#define N_HEADS 16
#define D_K     64
#define SEQ     2048
#define BATCH   4
#define EPS     1e-5f

typedef __attribute__((ext_vector_type(8))) short bf16x8;
typedef __attribute__((ext_vector_type(4))) float f32x4;

__device__ __forceinline__ unsigned short f2bf(float f) {
    unsigned u = __float_as_uint(f);
    u += 0x7fff + ((u >> 16) & 1);   // RNE
    return (unsigned short)(u >> 16);
}

#define GLDS16(g, l) __builtin_amdgcn_global_load_lds( \
    (const __attribute__((address_space(1))) void*)(g), \
    (__attribute__((address_space(3))) void*)(l), 16, 0, 0)

// ---------------------------------------------------------------------------
// f32 -> bf16 bulk convert (4 elems/thread)
// ---------------------------------------------------------------------------
__global__ __launch_bounds__(256) void cvt_f32_bf16(
    const float* __restrict__ in, unsigned short* __restrict__ out, int n4)
{
    int i = blockIdx.x * 256 + threadIdx.x;
    if (i >= n4) return;
    float4 f = ((const float4*)in)[i];
    union { ushort4 u; uint2 v; } o;
    o.u.x = f2bf(f.x); o.u.y = f2bf(f.y); o.u.z = f2bf(f.z); o.u.w = f2bf(f.w);
    ((uint2*)out)[i] = o.v;
}

// ---------------------------------------------------------------------------
// Fused QKV projection: Ot = x @ Wt^T + bt (bf16 out); Q scaled by 0.125.
// grid.x = 24 : [which 0..2][bn 0..7] ; grid.y = 64. 128x128 tile, BK=32.
// ---------------------------------------------------------------------------
__global__ __launch_bounds__(256) void gemm_qkv(
    const unsigned short* __restrict__ A,
    const unsigned short* __restrict__ Bq, const unsigned short* __restrict__ Bk,
    const unsigned short* __restrict__ Bv,
    const float* __restrict__ biq, const float* __restrict__ bik,
    const float* __restrict__ biv,
    unsigned short* __restrict__ Oq, unsigned short* __restrict__ Ok,
    unsigned short* __restrict__ Ov)
{
    const int which = blockIdx.x >> 3;
    const unsigned short* B = which == 0 ? Bq : (which == 1 ? Bk : Bv);
    const float* bias        = which == 0 ? biq : (which == 1 ? bik : biv);
    unsigned short* O        = which == 0 ? Oq : (which == 1 ? Ok : Ov);
    const float scale        = which == 0 ? 0.125f : 1.0f;

    __shared__ unsigned short As[128 * 32];
    __shared__ unsigned short Bs[128 * 32];
    const int tid = threadIdx.x;
    const int w = tid >> 6, lane = tid & 63;
    const int l15 = lane & 15, lh = lane >> 4;
    const int wm = w >> 1, wn = w & 1;
    const int bm = blockIdx.y * 128, bn = (blockIdx.x & 7) * 128;
    const int K = D_MODEL, N = D_MODEL;

    const int srow = lane >> 2;
    const int skk  = (lane & 3) * 8;

    f32x4 acc[4][4] = {};

    for (int k0 = 0; k0 < K; k0 += 32) {
#pragma unroll
        for (int cc = 0; cc < 2; ++cc) {
            int chunk = w * 2 + cc;
            int row = chunk * 16 + srow;
            GLDS16(A + (size_t)(bm + row) * K + k0 + skk, As + chunk * 512);
            GLDS16(B + (size_t)(bn + row) * K + k0 + skk, Bs + chunk * 512);
        }
        __syncthreads();
        bf16x8 af[4], bfr[4];
#pragma unroll
        for (int mi = 0; mi < 4; ++mi)
            af[mi] = *(const bf16x8*)&As[(wm * 64 + mi * 16 + l15) * 32 + lh * 8];
#pragma unroll
        for (int nj = 0; nj < 4; ++nj)
            bfr[nj] = *(const bf16x8*)&Bs[(wn * 64 + nj * 16 + l15) * 32 + lh * 8];
#pragma unroll
        for (int mi = 0; mi < 4; ++mi)
#pragma unroll
            for (int nj = 0; nj < 4; ++nj)
                acc[mi][nj] = __builtin_amdgcn_mfma_f32_16x16x32_bf16(
                    af[mi], bfr[nj], acc[mi][nj], 0, 0, 0);
        __syncthreads();
    }

#pragma unroll
    for (int mi = 0; mi < 4; ++mi) {
#pragma unroll
        for (int nj = 0; nj < 4; ++nj) {
            int col = bn + wn * 64 + nj * 16 + l15;
            float bv = bias[col];
#pragma unroll
            for (int r = 0; r < 4; ++r) {
                int row = bm + wm * 64 + mi * 16 + lh * 4 + r;
                O[(size_t)row * N + col] = f2bf((acc[mi][nj][r] + bv) * scale);
            }
        }
    }
}

// ---------------------------------------------------------------------------
// Output projection: C = ctx @ Wo^T + bo + residual (fp32 out). 128x128, BK=32.
// ---------------------------------------------------------------------------
__global__ __launch_bounds__(256) void gemm_out(
    const unsigned short* __restrict__ A, const unsigned short* __restrict__ B,
    const float* __restrict__ bias, const float* __restrict__ res,
    float* __restrict__ C)
{
    __shared__ unsigned short As[128 * 32];
    __shared__ unsigned short Bs[128 * 32];
    const int tid = threadIdx.x;
    const int w = tid >> 6, lane = tid & 63;
    const int l15 = lane & 15, lh = lane >> 4;
    const int wm = w >> 1, wn = w & 1;
    const int bm = blockIdx.y * 128, bn = blockIdx.x * 128;
    const int K = D_MODEL, N = D_MODEL;

    const int srow = lane >> 2;
    const int skk  = (lane & 3) * 8;

    f32x4 acc[4][4] = {};

    for (int k0 = 0; k0 < K; k0 += 32) {
#pragma unroll
        for (int cc = 0; cc < 2; ++cc) {
            int chunk = w * 2 + cc;
            int row = chunk * 16 + srow;
            GLDS16(A + (size_t)(bm + row) * K + k0 + skk, As + chunk * 512);
            GLDS16(B + (size_t)(bn + row) * K + k0 + skk, Bs + chunk * 512);
        }
        __syncthreads();
        bf16x8 af[4], bfr[4];
#pragma unroll
        for (int mi = 0; mi < 4; ++mi)
            af[mi] = *(const bf16x8*)&As[(wm * 64 + mi * 16 + l15) * 32 + lh * 8];
#pragma unroll
        for (int nj = 0; nj < 4; ++nj)
            bfr[nj] = *(const bf16x8*)&Bs[(wn * 64 + nj * 16 + l15) * 32 + lh * 8];
#pragma unroll
        for (int mi = 0; mi < 4; ++mi)
#pragma unroll
            for (int nj = 0; nj < 4; ++nj)
                acc[mi][nj] = __builtin_amdgcn_mfma_f32_16x16x32_bf16(
                    af[mi], bfr[nj], acc[mi][nj], 0, 0, 0);
        __syncthreads();
    }

#pragma unroll
    for (int mi = 0; mi < 4; ++mi) {
#pragma unroll
        for (int nj = 0; nj < 4; ++nj) {
            int col = bn + wn * 64 + nj * 16 + l15;
            float bv = bias[col];
#pragma unroll
            for (int r = 0; r < 4; ++r) {
                int row = bm + wm * 64 + mi * 16 + lh * 4 + r;
                C[(size_t)row * N + col] = acc[mi][nj][r] + bv + res[(size_t)row * N + col];
            }
        }
    }
}

// ---------------------------------------------------------------------------
// V transpose: v[b][s][h*64+d] -> vt[bh][d][s]   (coalesced both sides)
// ---------------------------------------------------------------------------
__global__ __launch_bounds__(256) void transpose_v(
    const unsigned short* __restrict__ v, unsigned short* __restrict__ vt)
{
    __shared__ unsigned short T[64][72];
    const int bh = blockIdx.y, b = bh >> 4, h = bh & 15;
    const int s0 = blockIdx.x * 64;
    const int tid = threadIdx.x;
#pragma unroll
    for (int i = 0; i < 2; ++i) {
        int idx = i * 256 + tid;          // 0..511
        int sr = idx >> 3, dc = idx & 7;
        uint4 t = *(const uint4*)(v + ((size_t)b * SEQ + s0 + sr) * D_MODEL + h * 64 + dc * 8);
        *(uint4*)&T[sr][dc * 8] = t;
    }
    __syncthreads();
#pragma unroll
    for (int i = 0; i < 2; ++i) {
        int idx = i * 256 + tid;
        int d = idx >> 3, sc = idx & 7;
        unsigned short tmp[8];
#pragma unroll
        for (int j = 0; j < 8; ++j) tmp[j] = T[sc * 8 + j][d];
        *(uint4*)(vt + ((size_t)bh * 64 + d) * SEQ + s0 + sc * 8) = *(uint4*)tmp;
    }
}

// ---------------------------------------------------------------------------
// Pass 0: invl[bh][q] = 1 / sum_k exp(s).  Wave-independent, no barriers.
// Wave owns 32 q-rows (2 sets of 16). K-frags direct from global (L2-hot).
// grid (SEQ/128, 64bh), 256 thr = 4 waves.
// ---------------------------------------------------------------------------
__global__ __launch_bounds__(256) void attn_pass0(
    const unsigned short* __restrict__ qb, const unsigned short* __restrict__ kb,
    float* __restrict__ invl)
{
    const int bh = blockIdx.y, b = bh >> 4, head = bh & 15;
    const int tid = threadIdx.x;
    const int w = tid >> 6, lane = tid & 63, l15 = lane & 15, lh = lane >> 4;
    const int bq = blockIdx.x * 128 + w * 32;
    const size_t rowbase = (size_t)b * SEQ;
    const unsigned short* Kh = kb + rowbase * D_MODEL + head * 64;

    bf16x8 aq[2][2];
#pragma unroll
    for (int qs = 0; qs < 2; ++qs)
#pragma unroll
        for (int kd = 0; kd < 2; ++kd)
            aq[qs][kd] = *(const bf16x8*)(qb + (rowbase + bq + qs * 16 + l15) * D_MODEL
                                          + head * 64 + kd * 32 + lh * 8);

    float rsum[2] = {0.f, 0.f};

    for (int kt = 0; kt < SEQ / 64; ++kt) {
        const int bk = kt * 64;
        f32x4 s[2][4] = {};
#pragma unroll
        for (int fj = 0; fj < 4; ++fj) {
            const unsigned short* kr = Kh + (size_t)(bk + fj * 16 + l15) * D_MODEL;
            bf16x8 kf0 = *(const bf16x8*)(kr + lh * 8);
            bf16x8 kf1 = *(const bf16x8*)(kr + 32 + lh * 8);
#pragma unroll
            for (int qs = 0; qs < 2; ++qs) {
                s[qs][fj] = __builtin_amdgcn_mfma_f32_16x16x32_bf16(kf0, aq[qs][0], s[qs][fj], 0, 0, 0);
                s[qs][fj] = __builtin_amdgcn_mfma_f32_16x16x32_bf16(kf1, aq[qs][1], s[qs][fj], 0, 0, 0);
            }
        }
#pragma unroll
        for (int qs = 0; qs < 2; ++qs)
#pragma unroll
            for (int fj = 0; fj < 4; ++fj)
                rsum[qs] += (__expf(s[qs][fj][0]) + __expf(s[qs][fj][1]))
                          + (__expf(s[qs][fj][2]) + __expf(s[qs][fj][3]));
    }

#pragma unroll
    for (int qs = 0; qs < 2; ++qs) {
        float v = rsum[qs];
        v += __shfl_xor(v, 16, 64);
        v += __shfl_xor(v, 32, 64);
        if (lh == 0)
            invl[(size_t)bh * SEQ + bq + qs * 16 + l15] = 1.0f / v;
    }
}

// ---------------------------------------------------------------------------
// Pass 1: recompute QK^T, P = exp(s)*invl (normalized at exp time),
// P -> wave-private LDS [32][72] (144B stride: all access patterns bank-optimal),
// PV via pre-transposed V^T (direct global), P -> global fp32 (256B segments).
// Wave-independent, NO barriers. grid (SEQ/128, 64bh).
// ---------------------------------------------------------------------------
__global__ __launch_bounds__(256) void attn_pass1(
    const unsigned short* __restrict__ qb, const unsigned short* __restrict__ kb,
    const unsigned short* __restrict__ vt, const float* __restrict__ invl,
    float* __restrict__ attnP, unsigned short* __restrict__ ctx)
{
    __shared__ unsigned short Ps[4][32][72];
    const int bh = blockIdx.y, b = bh >> 4, head = bh & 15;
    const int tid = threadIdx.x;
    const int w = tid >> 6, lane = tid & 63, l15 = lane & 15, lh = lane >> 4;
    const int bq = blockIdx.x * 128 + w * 32;
    const size_t rowbase = (size_t)b * SEQ;
    const unsigned short* Kh = kb + rowbase * D_MODEL + head * 64;
    const unsigned short* Vh = vt + (size_t)bh * 64 * SEQ;    // [d][s]
    char* myPs = (char*)&Ps[w][0][0];

    bf16x8 aq[2][2];
    float invr[2];
#pragma unroll
    for (int qs = 0; qs < 2; ++qs) {
#pragma unroll
        for (int kd = 0; kd < 2; ++kd)
            aq[qs][kd] = *(const bf16x8*)(qb + (rowbase + bq + qs * 16 + l15) * D_MODEL
                                          + head * 64 + kd * 32 + lh * 8);
        invr[qs] = invl[(size_t)bh * SEQ + bq + qs * 16 + l15];
    }

    f32x4 acc[2][4] = {};   // [qset][d-block]

    for (int kt = 0; kt < SEQ / 64; ++kt) {
        const int bk = kt * 64;

        // ---- QK^T : S^T[key][q] ----
        f32x4 s[2][4] = {};
#pragma unroll
        for (int fj = 0; fj < 4; ++fj) {
            const unsigned short* kr = Kh + (size_t)(bk + fj * 16 + l15) * D_MODEL;
            bf16x8 kf0 = *(const bf16x8*)(kr + lh * 8);
            bf16x8 kf1 = *(const bf16x8*)(kr + 32 + lh * 8);
#pragma unroll
            for (int qs = 0; qs < 2; ++qs) {
                s[qs][fj] = __builtin_amdgcn_mfma_f32_16x16x32_bf16(kf0, aq[qs][0], s[qs][fj], 0, 0, 0);
                s[qs][fj] = __builtin_amdgcn_mfma_f32_16x16x32_bf16(kf1, aq[qs][1], s[qs][fj], 0, 0, 0);
            }
        }

        // ---- exp, normalize, pack to LDS (lane l15 = q, keys fj*16+lh*4+r) ----
#pragma unroll
        for (int qs = 0; qs < 2; ++qs)
#pragma unroll
            for (int fj = 0; fj < 4; ++fj) {
                float p0 = __expf(s[qs][fj][0]) * invr[qs];
                float p1 = __expf(s[qs][fj][1]) * invr[qs];
                float p2 = __expf(s[qs][fj][2]) * invr[qs];
                float p3 = __expf(s[qs][fj][3]) * invr[qs];
                uint2 pk;
                pk.x = ((unsigned)f2bf(p1) << 16) | f2bf(p0);
                pk.y = ((unsigned)f2bf(p3) << 16) | f2bf(p2);
                *(uint2*)(myPs + (qs * 16 + l15) * 144 + fj * 32 + lh * 8) = pk;
            }

        // ---- PV : O^T[d][q] += V^T[d][key] * P^T[key][q] ----
        bf16x8 pb[2][2];
#pragma unroll
        for (int qs = 0; qs < 2; ++qs)
#pragma unroll
            for (int ks = 0; ks < 2; ++ks)
                pb[qs][ks] = *(const bf16x8*)(myPs + (qs * 16 + l15) * 144 + ks * 64 + lh * 16);
#pragma unroll
        for (int db = 0; db < 4; ++db) {
            const unsigned short* vr = Vh + (size_t)(db * 16 + l15) * SEQ + bk;
            bf16x8 va0 = *(const bf16x8*)(vr + lh * 8);
            bf16x8 va1 = *(const bf16x8*)(vr + 32 + lh * 8);
#pragma unroll
            for (int qs = 0; qs < 2; ++qs) {
                acc[qs][db] = __builtin_amdgcn_mfma_f32_16x16x32_bf16(va0, pb[qs][0], acc[qs][db], 0, 0, 0);
                acc[qs][db] = __builtin_amdgcn_mfma_f32_16x16x32_bf16(va1, pb[qs][1], acc[qs][db], 0, 0, 0);
            }
        }

        // ---- P tile -> global fp32 (row q: 4 lanes x 64B = 256B contiguous) ----
#pragma unroll
        for (int qs = 0; qs < 2; ++qs) {
            int qq = lane >> 2, c4 = lane & 3;
            const char* ps = myPs + (qs * 16 + qq) * 144 + c4 * 32;
            uint4 a0 = *(const uint4*)ps;
            uint4 a1 = *(const uint4*)(ps + 16);
            const unsigned* ua = (const unsigned*)&a0;
            const unsigned* ub = (const unsigned*)&a1;
            float f[16];
#pragma unroll
            for (int j = 0; j < 4; ++j) {
                f[2 * j]         = __uint_as_float(ua[j] << 16);
                f[2 * j + 1]     = __uint_as_float(ua[j] & 0xffff0000u);
                f[8 + 2 * j]     = __uint_as_float(ub[j] << 16);
                f[8 + 2 * j + 1] = __uint_as_float(ub[j] & 0xffff0000u);
            }
            float* dst = attnP + ((size_t)bh * SEQ + bq + qs * 16 + qq) * SEQ + bk + c4 * 16;
#pragma unroll
            for (int j4 = 0; j4 < 4; ++j4)
                *(float4*)(dst + j4 * 4) = *(float4*)&f[j4 * 4];
        }
    }

    // ---- ctx write: lane l15 = q, d = db*16 + lh*4 + r ----
#pragma unroll
    for (int qs = 0; qs < 2; ++qs)
#pragma unroll
        for (int db = 0; db < 4; ++db) {
            union { ushort4 u; uint2 v; } o;
            o.u.x = f2bf(acc[qs][db][0]); o.u.y = f2bf(acc[qs][db][1]);
            o.u.z = f2bf(acc[qs][db][2]); o.u.w = f2bf(acc[qs][db][3]);
            *(uint2*)&ctx[(rowbase + bq + qs * 16 + l15) * D_MODEL + head * 64 + db * 16 + lh * 4] = o.v;
        }
}

// ---------------------------------------------------------------------------
// LayerNorm over last dim (1024). 1 block/row.
// ---------------------------------------------------------------------------
__global__ __launch_bounds__(256) void layernorm_rows(
    const float* __restrict__ h, const float* __restrict__ gamma,
    const float* __restrict__ beta, float* __restrict__ out)
{
    const size_t row = blockIdx.x;
    const float* hr = h + row * D_MODEL;
    const int tid = threadIdx.x;

    float v[4];
    float s = 0.f;
#pragma unroll
    for (int i = 0; i < 4; ++i) { v[i] = hr[tid + i * 256]; s += v[i]; }
    __shared__ float red[256];
    red[tid] = s;
    __syncthreads();
    for (int st = 128; st > 0; st >>= 1) {
        if (tid < st) red[tid] += red[tid + st];
        __syncthreads();
    }
    float mean = red[0] * (1.0f / D_MODEL);
    __syncthreads();

    float vs = 0.f;
#pragma unroll
    for (int i = 0; i < 4; ++i) { float d = v[i] - mean; vs += d * d; }
    red[tid] = vs;
    __syncthreads();
    for (int st = 128; st > 0; st >>= 1) {
        if (tid < st) red[tid] += red[tid + st];
        __syncthreads();
    }
    float inv = rsqrtf(red[0] * (1.0f / D_MODEL) + EPS);

#pragma unroll
    for (int i = 0; i < 4; ++i) {
        int c = tid + i * 256;
        out[row * D_MODEL + c] = (v[i] - mean) * inv * gamma[c] + beta[c];
    }
}

// ---------------------------------------------------------------------------
extern "C" void kernel_launch(void* const* d_in, const int* in_sizes, int n_in,
                              void* d_out, int out_size, void* d_ws, size_t ws_size,
                              hipStream_t stream)
{
    const float* x     = (const float*)d_in[0];
    const float* Wq    = (const float*)d_in[1];
    const float* bq_   = (const float*)d_in[2];
    const float* Wk    = (const float*)d_in[3];
    const float* bk_   = (const float*)d_in[4];
    const float* Wv    = (const float*)d_in[5];
    const float* bv_   = (const float*)d_in[6];
    const float* Wo    = (const float*)d_in[7];
    const float* bo_   = (const float*)d_in[8];
    const float* gamma = (const float*)d_in[9];
    const float* beta  = (const float*)d_in[10];

    const size_t NX = (size_t)BATCH * SEQ * D_MODEL;   // 8388608
    const size_t NW = (size_t)D_MODEL * D_MODEL;       // 1048576

    float* out_ln = (float*)d_out;
    float* attnP  = out_ln + NX;

    unsigned short* x_bf   = (unsigned short*)d_ws;    // aliased as vt after gemm_qkv
    unsigned short* wq_bf  = x_bf + NX;
    unsigned short* wk_bf  = wq_bf + NW;
    unsigned short* wv_bf  = wk_bf + NW;
    unsigned short* wo_bf  = wv_bf + NW;
    unsigned short* q_bf   = wo_bf + NW;
    unsigned short* k_bf   = q_bf + NX;
    unsigned short* v_bf   = k_bf + NX;
    unsigned short* ctx_bf = v_bf + NX;
    float* invl = (float*)(ctx_bf + NX);               // 64*2048 f32
    unsigned short* vt_bf = x_bf;                      // reuse x_bf region
    float* hbuf = (float*)q_bf;                        // reuse q+k region (f32 NX)

    const int M = BATCH * SEQ;   // 8192

    cvt_f32_bf16<<<(int)(NX / 4 / 256), 256, 0, stream>>>(x, x_bf, (int)(NX / 4));
    cvt_f32_bf16<<<(int)(NW / 4 / 256), 256, 0, stream>>>(Wq, wq_bf, (int)(NW / 4));
    cvt_f32_bf16<<<(int)(NW / 4 / 256), 256, 0, stream>>>(Wk, wk_bf, (int)(NW / 4));
    cvt_f32_bf16<<<(int)(NW / 4 / 256), 256, 0, stream>>>(Wv, wv_bf, (int)(NW / 4));
    cvt_f32_bf16<<<(int)(NW / 4 / 256), 256, 0, stream>>>(Wo, wo_bf, (int)(NW / 4));

    gemm_qkv<<<dim3(24, M / 128), 256, 0, stream>>>(
        x_bf, wq_bf, wk_bf, wv_bf, bq_, bk_, bv_, q_bf, k_bf, v_bf);

    transpose_v<<<dim3(SEQ / 64, BATCH * N_HEADS), 256, 0, stream>>>(v_bf, vt_bf);

    attn_pass0<<<dim3(SEQ / 128, BATCH * N_HEADS), 256, 0, stream>>>(q_bf, k_bf, invl);

    attn_pass1<<<dim3(SEQ / 128, BATCH * N_HEADS), 256, 0, stream>>>(
        q_bf, k_bf, vt_bf, invl, attnP, ctx_bf);

    gemm_out<<<dim3(D_MODEL / 128, M / 128), 256, 0, stream>>>(
        ctx_bf, wo_bf, bo_, x, hbuf);

    layernorm_rows<<<M, 256, 0, stream>>>(hbuf, gamma, beta, out_ln);
}

// Round 5
// 533.590 us; speedup vs baseline: 2.2785x; 1.5758x over previous
//
#include <hip/hip_runtime.h>
#include <math.h>

#define D_MODEL 1024
#define N_HEADS 16
#define D_K     64
#define SEQ     2048
#define BATCH   4
#define EPS     1e-5f
#define NT      (SEQ / 64)   // 32 key-tiles

typedef __attribute__((ext_vector_type(8))) short bf16x8;
typedef __attribute__((ext_vector_type(4))) float f32x4;

__device__ __forceinline__ unsigned short f2bf(float f) {
    unsigned u = __float_as_uint(f);
    u += 0x7fff + ((u >> 16) & 1);   // RNE
    return (unsigned short)(u >> 16);
}

#define GLDS16(g, l) __builtin_amdgcn_global_load_lds( \
    (const __attribute__((address_space(1))) void*)(g), \
    (__attribute__((address_space(3))) void*)(l), 16, 0, 0)

// ---------------------------------------------------------------------------
// f32 -> bf16 bulk convert (4 elems/thread)
// ---------------------------------------------------------------------------
__global__ __launch_bounds__(256) void cvt_f32_bf16(
    const float* __restrict__ in, unsigned short* __restrict__ out, int n4)
{
    int i = blockIdx.x * 256 + threadIdx.x;
    if (i >= n4) return;
    float4 f = ((const float4*)in)[i];
    union { ushort4 u; uint2 v; } o;
    o.u.x = f2bf(f.x); o.u.y = f2bf(f.y); o.u.z = f2bf(f.z); o.u.w = f2bf(f.w);
    ((uint2*)out)[i] = o.v;
}

// ---------------------------------------------------------------------------
// Fused QKV projection: Ot = x @ Wt^T + bt (bf16 out); Q scaled by 0.125.
// grid.x = 24 : [which 0..2][bn 0..7] ; grid.y = 64. 128x128 tile, BK=32.
// ---------------------------------------------------------------------------
__global__ __launch_bounds__(256) void gemm_qkv(
    const unsigned short* __restrict__ A,
    const unsigned short* __restrict__ Bq, const unsigned short* __restrict__ Bk,
    const unsigned short* __restrict__ Bv,
    const float* __restrict__ biq, const float* __restrict__ bik,
    const float* __restrict__ biv,
    unsigned short* __restrict__ Oq, unsigned short* __restrict__ Ok,
    unsigned short* __restrict__ Ov)
{
    const int which = blockIdx.x >> 3;
    const unsigned short* B = which == 0 ? Bq : (which == 1 ? Bk : Bv);
    const float* bias        = which == 0 ? biq : (which == 1 ? bik : biv);
    unsigned short* O        = which == 0 ? Oq : (which == 1 ? Ok : Ov);
    const float scale        = which == 0 ? 0.125f : 1.0f;

    __shared__ unsigned short As[128 * 32];
    __shared__ unsigned short Bs[128 * 32];
    const int tid = threadIdx.x;
    const int w = tid >> 6, lane = tid & 63;
    const int l15 = lane & 15, lh = lane >> 4;
    const int wm = w >> 1, wn = w & 1;
    const int bm = blockIdx.y * 128, bn = (blockIdx.x & 7) * 128;
    const int K = D_MODEL, N = D_MODEL;

    const int srow = lane >> 2;
    const int skk  = (lane & 3) * 8;

    f32x4 acc[4][4] = {};

    for (int k0 = 0; k0 < K; k0 += 32) {
#pragma unroll
        for (int cc = 0; cc < 2; ++cc) {
            int chunk = w * 2 + cc;
            int row = chunk * 16 + srow;
            GLDS16(A + (size_t)(bm + row) * K + k0 + skk, As + chunk * 512);
            GLDS16(B + (size_t)(bn + row) * K + k0 + skk, Bs + chunk * 512);
        }
        __syncthreads();
        bf16x8 af[4], bfr[4];
#pragma unroll
        for (int mi = 0; mi < 4; ++mi)
            af[mi] = *(const bf16x8*)&As[(wm * 64 + mi * 16 + l15) * 32 + lh * 8];
#pragma unroll
        for (int nj = 0; nj < 4; ++nj)
            bfr[nj] = *(const bf16x8*)&Bs[(wn * 64 + nj * 16 + l15) * 32 + lh * 8];
#pragma unroll
        for (int mi = 0; mi < 4; ++mi)
#pragma unroll
            for (int nj = 0; nj < 4; ++nj)
                acc[mi][nj] = __builtin_amdgcn_mfma_f32_16x16x32_bf16(
                    af[mi], bfr[nj], acc[mi][nj], 0, 0, 0);
        __syncthreads();
    }

#pragma unroll
    for (int mi = 0; mi < 4; ++mi) {
#pragma unroll
        for (int nj = 0; nj < 4; ++nj) {
            int col = bn + wn * 64 + nj * 16 + l15;
            float bv = bias[col];
#pragma unroll
            for (int r = 0; r < 4; ++r) {
                int row = bm + wm * 64 + mi * 16 + lh * 4 + r;
                O[(size_t)row * N + col] = f2bf((acc[mi][nj][r] + bv) * scale);
            }
        }
    }
}

// ---------------------------------------------------------------------------
// Output projection: C = ctx @ Wo^T + bo + residual (fp32 out). 128x128, BK=32.
// ---------------------------------------------------------------------------
__global__ __launch_bounds__(256) void gemm_out(
    const unsigned short* __restrict__ A, const unsigned short* __restrict__ B,
    const float* __restrict__ bias, const float* __restrict__ res,
    float* __restrict__ C)
{
    __shared__ unsigned short As[128 * 32];
    __shared__ unsigned short Bs[128 * 32];
    const int tid = threadIdx.x;
    const int w = tid >> 6, lane = tid & 63;
    const int l15 = lane & 15, lh = lane >> 4;
    const int wm = w >> 1, wn = w & 1;
    const int bm = blockIdx.y * 128, bn = blockIdx.x * 128;
    const int K = D_MODEL, N = D_MODEL;

    const int srow = lane >> 2;
    const int skk  = (lane & 3) * 8;

    f32x4 acc[4][4] = {};

    for (int k0 = 0; k0 < K; k0 += 32) {
#pragma unroll
        for (int cc = 0; cc < 2; ++cc) {
            int chunk = w * 2 + cc;
            int row = chunk * 16 + srow;
            GLDS16(A + (size_t)(bm + row) * K + k0 + skk, As + chunk * 512);
            GLDS16(B + (size_t)(bn + row) * K + k0 + skk, Bs + chunk * 512);
        }
        __syncthreads();
        bf16x8 af[4], bfr[4];
#pragma unroll
        for (int mi = 0; mi < 4; ++mi)
            af[mi] = *(const bf16x8*)&As[(wm * 64 + mi * 16 + l15) * 32 + lh * 8];
#pragma unroll
        for (int nj = 0; nj < 4; ++nj)
            bfr[nj] = *(const bf16x8*)&Bs[(wn * 64 + nj * 16 + l15) * 32 + lh * 8];
#pragma unroll
        for (int mi = 0; mi < 4; ++mi)
#pragma unroll
            for (int nj = 0; nj < 4; ++nj)
                acc[mi][nj] = __builtin_amdgcn_mfma_f32_16x16x32_bf16(
                    af[mi], bfr[nj], acc[mi][nj], 0, 0, 0);
        __syncthreads();
    }

#pragma unroll
    for (int mi = 0; mi < 4; ++mi) {
#pragma unroll
        for (int nj = 0; nj < 4; ++nj) {
            int col = bn + wn * 64 + nj * 16 + l15;
            float bv = bias[col];
#pragma unroll
            for (int r = 0; r < 4; ++r) {
                int row = bm + wm * 64 + mi * 16 + lh * 4 + r;
                C[(size_t)row * N + col] = acc[mi][nj][r] + bv + res[(size_t)row * N + col];
            }
        }
    }
}

// ---------------------------------------------------------------------------
// V transpose: v[b][s][h*64+d] -> vt[bh][d][s]   (coalesced both sides)
// ---------------------------------------------------------------------------
__global__ __launch_bounds__(256) void transpose_v(
    const unsigned short* __restrict__ v, unsigned short* __restrict__ vt)
{
    __shared__ unsigned short T[64][72];
    const int bh = blockIdx.y, b = bh >> 4, h = bh & 15;
    const int s0 = blockIdx.x * 64;
    const int tid = threadIdx.x;
#pragma unroll
    for (int i = 0; i < 2; ++i) {
        int idx = i * 256 + tid;          // 0..511
        int sr = idx >> 3, dc = idx & 7;
        uint4 t = *(const uint4*)(v + ((size_t)b * SEQ + s0 + sr) * D_MODEL + h * 64 + dc * 8);
        *(uint4*)&T[sr][dc * 8] = t;
    }
    __syncthreads();
#pragma unroll
    for (int i = 0; i < 2; ++i) {
        int idx = i * 256 + tid;
        int d = idx >> 3, sc = idx & 7;
        unsigned short tmp[8];
#pragma unroll
        for (int j = 0; j < 8; ++j) tmp[j] = T[sc * 8 + j][d];
        *(uint4*)(vt + ((size_t)bh * 64 + d) * SEQ + s0 + sc * 8) = *(uint4*)tmp;
    }
}

// ---------------------------------------------------------------------------
// Staging helper: stage a 64-row x 128B tile into LDS (linear dest,
// chunk-swizzled global source: lds chunk cs <- global chunk cs ^ (row&7)).
// Read side XORs the same involution -> conflict-free ds_read_b128.
// ---------------------------------------------------------------------------
__device__ __forceinline__ void stage_tile64(
    const unsigned short* __restrict__ gbase, size_t grow_stride,
    unsigned short* lds, int w, int lane)
{
#pragma unroll
    for (int i = 0; i < 2; ++i) {
        int row = i * 32 + w * 8 + (lane >> 3);
        int c   = (lane & 7) ^ (row & 7);
        GLDS16(gbase + (size_t)row * grow_stride + c * 8,
               lds + (size_t)(i * 256 + w * 64) * 8);
    }
}

// ---------------------------------------------------------------------------
// Pass 0: invl[bh][q] = 1 / sum_k exp(s).  QBLK=128 (4 waves x 32 q-rows).
// K tile LDS-staged, double-buffered, 1 barrier/tile.
// grid (64 bh, SEQ/128) -> bid%8 = bh%8 pins each head's K to one XCD L2.
// ---------------------------------------------------------------------------
__global__ __launch_bounds__(256) void attn_pass0(
    const unsigned short* __restrict__ qb, const unsigned short* __restrict__ kb,
    float* __restrict__ invl)
{
    __shared__ unsigned short Ks[2][64 * 64];   // 8 KB each
    const int bh = blockIdx.x, b = bh >> 4, head = bh & 15;
    const int tid = threadIdx.x;
    const int w = tid >> 6, lane = tid & 63, l15 = lane & 15, lh = lane >> 4;
    const int bq = blockIdx.y * 128 + w * 32;
    const size_t rowbase = (size_t)b * SEQ;
    const unsigned short* Kh = kb + rowbase * D_MODEL + head * 64;

    bf16x8 aq[2][2];
#pragma unroll
    for (int qs = 0; qs < 2; ++qs)
#pragma unroll
        for (int kd = 0; kd < 2; ++kd)
            aq[qs][kd] = *(const bf16x8*)(qb + (rowbase + bq + qs * 16 + l15) * D_MODEL
                                          + head * 64 + kd * 32 + lh * 8);

    float rsum[2] = {0.f, 0.f};

    stage_tile64(Kh, D_MODEL, Ks[0], w, lane);
    __syncthreads();

    for (int kt = 0; kt < NT; ++kt) {
        const int cur = kt & 1;
        if (kt + 1 < NT)
            stage_tile64(Kh + (size_t)(kt + 1) * 64 * D_MODEL, D_MODEL, Ks[cur ^ 1], w, lane);

        const char* kbuf = (const char*)Ks[cur];
        f32x4 s[2][4] = {};
#pragma unroll
        for (int fj = 0; fj < 4; ++fj) {
            int key = fj * 16 + l15;
            bf16x8 kf0 = *(const bf16x8*)(kbuf + key * 128 + ((lh ^ (key & 7)) << 4));
            bf16x8 kf1 = *(const bf16x8*)(kbuf + key * 128 + (((4 + lh) ^ (key & 7)) << 4));
#pragma unroll
            for (int qs = 0; qs < 2; ++qs) {
                s[qs][fj] = __builtin_amdgcn_mfma_f32_16x16x32_bf16(kf0, aq[qs][0], s[qs][fj], 0, 0, 0);
                s[qs][fj] = __builtin_amdgcn_mfma_f32_16x16x32_bf16(kf1, aq[qs][1], s[qs][fj], 0, 0, 0);
            }
        }
#pragma unroll
        for (int qs = 0; qs < 2; ++qs)
#pragma unroll
            for (int fj = 0; fj < 4; ++fj)
                rsum[qs] += (__expf(s[qs][fj][0]) + __expf(s[qs][fj][1]))
                          + (__expf(s[qs][fj][2]) + __expf(s[qs][fj][3]));
        __syncthreads();
    }

#pragma unroll
    for (int qs = 0; qs < 2; ++qs) {
        float v = rsum[qs];
        v += __shfl_xor(v, 16, 64);
        v += __shfl_xor(v, 32, 64);
        if (lh == 0)
            invl[(size_t)bh * SEQ + bq + qs * 16 + l15] = 1.0f / v;
    }
}

// ---------------------------------------------------------------------------
// Pass 1: QK^T (recomputed), P = exp(s)*invl written to global DIRECTLY from
// registers (fp32x4/lane, 64B segments); PV B-operand re-layout via small
// wave-private LDS Ps[32][144B]; K and V^T tiles LDS-staged double-buffered.
// grid (64 bh, SEQ/128). 1 barrier/tile. LDS 50 KB -> 3 blocks/CU.
// ---------------------------------------------------------------------------
__global__ __launch_bounds__(256) void attn_pass1(
    const unsigned short* __restrict__ qb, const unsigned short* __restrict__ kb,
    const unsigned short* __restrict__ vt, const float* __restrict__ invl,
    float* __restrict__ attnP, unsigned short* __restrict__ ctx)
{
    __shared__ unsigned short Ks[2][64 * 64];   // 8 KB each
    __shared__ unsigned short Vs[2][64 * 64];   // 8 KB each (V^T rows = d)
    __shared__ unsigned short Ps[4][32 * 72];   // wave-private, 144B row stride
    const int bh = blockIdx.x, b = bh >> 4, head = bh & 15;
    const int tid = threadIdx.x;
    const int w = tid >> 6, lane = tid & 63, l15 = lane & 15, lh = lane >> 4;
    const int bq = blockIdx.y * 128 + w * 32;
    const size_t rowbase = (size_t)b * SEQ;
    const unsigned short* Kh = kb + rowbase * D_MODEL + head * 64;
    const unsigned short* Vh = vt + (size_t)bh * 64 * SEQ;    // [d][s]
    char* myPs = (char*)&Ps[w][0];

    bf16x8 aq[2][2];
    float invr[2];
    float* pdst[2];
#pragma unroll
    for (int qs = 0; qs < 2; ++qs) {
#pragma unroll
        for (int kd = 0; kd < 2; ++kd)
            aq[qs][kd] = *(const bf16x8*)(qb + (rowbase + bq + qs * 16 + l15) * D_MODEL
                                          + head * 64 + kd * 32 + lh * 8);
        invr[qs] = invl[(size_t)bh * SEQ + bq + qs * 16 + l15];
        pdst[qs] = attnP + ((size_t)bh * SEQ + bq + qs * 16 + l15) * SEQ + lh * 4;
    }

    f32x4 acc[2][4] = {};   // [qset][d-block]

    stage_tile64(Kh, D_MODEL, Ks[0], w, lane);
    stage_tile64(Vh, SEQ,     Vs[0], w, lane);
    __syncthreads();

    for (int kt = 0; kt < NT; ++kt) {
        const int cur = kt & 1;
        const int bk = kt * 64;
        if (kt + 1 < NT) {
            stage_tile64(Kh + (size_t)(bk + 64) * D_MODEL, D_MODEL, Ks[cur ^ 1], w, lane);
            stage_tile64(Vh + (size_t)(bk + 64),           SEQ,     Vs[cur ^ 1], w, lane);
        }

        // ---- QK^T : S^T[key][q] ----
        const char* kbuf = (const char*)Ks[cur];
        f32x4 s[2][4] = {};
#pragma unroll
        for (int fj = 0; fj < 4; ++fj) {
            int key = fj * 16 + l15;
            bf16x8 kf0 = *(const bf16x8*)(kbuf + key * 128 + ((lh ^ (key & 7)) << 4));
            bf16x8 kf1 = *(const bf16x8*)(kbuf + key * 128 + (((4 + lh) ^ (key & 7)) << 4));
#pragma unroll
            for (int qs = 0; qs < 2; ++qs) {
                s[qs][fj] = __builtin_amdgcn_mfma_f32_16x16x32_bf16(kf0, aq[qs][0], s[qs][fj], 0, 0, 0);
                s[qs][fj] = __builtin_amdgcn_mfma_f32_16x16x32_bf16(kf1, aq[qs][1], s[qs][fj], 0, 0, 0);
            }
        }

        // ---- exp*invl: P -> global fp32 direct from regs; bf16 pack -> Ps ----
#pragma unroll
        for (int qs = 0; qs < 2; ++qs) {
#pragma unroll
            for (int fj = 0; fj < 4; ++fj) {
                float p0 = __expf(s[qs][fj][0]) * invr[qs];
                float p1 = __expf(s[qs][fj][1]) * invr[qs];
                float p2 = __expf(s[qs][fj][2]) * invr[qs];
                float p3 = __expf(s[qs][fj][3]) * invr[qs];
                float4 st = {p0, p1, p2, p3};
                *(float4*)(pdst[qs] + bk + fj * 16) = st;
                uint2 pk;
                pk.x = ((unsigned)f2bf(p1) << 16) | f2bf(p0);
                pk.y = ((unsigned)f2bf(p3) << 16) | f2bf(p2);
                *(uint2*)(myPs + (qs * 16 + l15) * 144 + fj * 32 + lh * 8) = pk;
            }
        }

        // ---- PV : O^T[d][q] += V^T[d][key] * P^T[key][q] ----
        const char* vbuf = (const char*)Vs[cur];
        bf16x8 pb[2][2];
#pragma unroll
        for (int qs = 0; qs < 2; ++qs)
#pragma unroll
            for (int ks = 0; ks < 2; ++ks)
                pb[qs][ks] = *(const bf16x8*)(myPs + (qs * 16 + l15) * 144 + ks * 64 + lh * 16);
#pragma unroll
        for (int db = 0; db < 4; ++db) {
            int d = db * 16 + l15;
            bf16x8 va0 = *(const bf16x8*)(vbuf + d * 128 + ((lh ^ (d & 7)) << 4));
            bf16x8 va1 = *(const bf16x8*)(vbuf + d * 128 + (((4 + lh) ^ (d & 7)) << 4));
#pragma unroll
            for (int qs = 0; qs < 2; ++qs) {
                acc[qs][db] = __builtin_amdgcn_mfma_f32_16x16x32_bf16(va0, pb[qs][0], acc[qs][db], 0, 0, 0);
                acc[qs][db] = __builtin_amdgcn_mfma_f32_16x16x32_bf16(va1, pb[qs][1], acc[qs][db], 0, 0, 0);
            }
        }
        __syncthreads();
    }

    // ---- ctx write: lane l15 = q, d = db*16 + lh*4 + r ----
#pragma unroll
    for (int qs = 0; qs < 2; ++qs)
#pragma unroll
        for (int db = 0; db < 4; ++db) {
            union { ushort4 u; uint2 v; } o;
            o.u.x = f2bf(acc[qs][db][0]); o.u.y = f2bf(acc[qs][db][1]);
            o.u.z = f2bf(acc[qs][db][2]); o.u.w = f2bf(acc[qs][db][3]);
            *(uint2*)&ctx[(rowbase + bq + qs * 16 + l15) * D_MODEL + head * 64 + db * 16 + lh * 4] = o.v;
        }
}

// ---------------------------------------------------------------------------
// LayerNorm over last dim (1024). 1 block/row.
// ---------------------------------------------------------------------------
__global__ __launch_bounds__(256) void layernorm_rows(
    const float* __restrict__ h, const float* __restrict__ gamma,
    const float* __restrict__ beta, float* __restrict__ out)
{
    const size_t row = blockIdx.x;
    const float* hr = h + row * D_MODEL;
    const int tid = threadIdx.x;

    float v[4];
    float s = 0.f;
#pragma unroll
    for (int i = 0; i < 4; ++i) { v[i] = hr[tid + i * 256]; s += v[i]; }
    __shared__ float red[256];
    red[tid] = s;
    __syncthreads();
    for (int st = 128; st > 0; st >>= 1) {
        if (tid < st) red[tid] += red[tid + st];
        __syncthreads();
    }
    float mean = red[0] * (1.0f / D_MODEL);
    __syncthreads();

    float vs = 0.f;
#pragma unroll
    for (int i = 0; i < 4; ++i) { float d = v[i] - mean; vs += d * d; }
    red[tid] = vs;
    __syncthreads();
    for (int st = 128; st > 0; st >>= 1) {
        if (tid < st) red[tid] += red[tid + st];
        __syncthreads();
    }
    float inv = rsqrtf(red[0] * (1.0f / D_MODEL) + EPS);

#pragma unroll
    for (int i = 0; i < 4; ++i) {
        int c = tid + i * 256;
        out[row * D_MODEL + c] = (v[i] - mean) * inv * gamma[c] + beta[c];
    }
}

// ---------------------------------------------------------------------------
extern "C" void kernel_launch(void* const* d_in, const int* in_sizes, int n_in,
                              void* d_out, int out_size, void* d_ws, size_t ws_size,
                              hipStream_t stream)
{
    const float* x     = (const float*)d_in[0];
    const float* Wq    = (const float*)d_in[1];
    const float* bq_   = (const float*)d_in[2];
    const float* Wk    = (const float*)d_in[3];
    const float* bk_   = (const float*)d_in[4];
    const float* Wv    = (const float*)d_in[5];
    const float* bv_   = (const float*)d_in[6];
    const float* Wo    = (const float*)d_in[7];
    const float* bo_   = (const float*)d_in[8];
    const float* gamma = (const float*)d_in[9];
    const float* beta  = (const float*)d_in[10];

    const size_t NX = (size_t)BATCH * SEQ * D_MODEL;   // 8388608
    const size_t NW = (size_t)D_MODEL * D_MODEL;       // 1048576

    float* out_ln = (float*)d_out;
    float* attnP  = out_ln + NX;

    unsigned short* x_bf   = (unsigned short*)d_ws;    // aliased as vt after gemm_qkv
    unsigned short* wq_bf  = x_bf + NX;
    unsigned short* wk_bf  = wq_bf + NW;
    unsigned short* wv_bf  = wk_bf + NW;
    unsigned short* wo_bf  = wv_bf + NW;
    unsigned short* q_bf   = wo_bf + NW;
    unsigned short* k_bf   = q_bf + NX;
    unsigned short* v_bf   = k_bf + NX;
    unsigned short* ctx_bf = v_bf + NX;
    float* invl = (float*)(ctx_bf + NX);               // 64*2048 f32
    unsigned short* vt_bf = x_bf;                      // reuse x_bf region
    float* hbuf = (float*)q_bf;                        // reuse q+k region (f32 NX)

    const int M = BATCH * SEQ;   // 8192

    cvt_f32_bf16<<<(int)(NX / 4 / 256), 256, 0, stream>>>(x, x_bf, (int)(NX / 4));
    cvt_f32_bf16<<<(int)(NW / 4 / 256), 256, 0, stream>>>(Wq, wq_bf, (int)(NW / 4));
    cvt_f32_bf16<<<(int)(NW / 4 / 256), 256, 0, stream>>>(Wk, wk_bf, (int)(NW / 4));
    cvt_f32_bf16<<<(int)(NW / 4 / 256), 256, 0, stream>>>(Wv, wv_bf, (int)(NW / 4));
    cvt_f32_bf16<<<(int)(NW / 4 / 256), 256, 0, stream>>>(Wo, wo_bf, (int)(NW / 4));

    gemm_qkv<<<dim3(24, M / 128), 256, 0, stream>>>(
        x_bf, wq_bf, wk_bf, wv_bf, bq_, bk_, bv_, q_bf, k_bf, v_bf);

    transpose_v<<<dim3(SEQ / 64, BATCH * N_HEADS), 256, 0, stream>>>(v_bf, vt_bf);

    attn_pass0<<<dim3(BATCH * N_HEADS, SEQ / 128), 256, 0, stream>>>(q_bf, k_bf, invl);

    attn_pass1<<<dim3(BATCH * N_HEADS, SEQ / 128), 256, 0, stream>>>(
        q_bf, k_bf, vt_bf, invl, attnP, ctx_bf);

    gemm_out<<<dim3(D_MODEL / 128, M / 128), 256, 0, stream>>>(
        ctx_bf, wo_bf, bo_, x, hbuf);

    layernorm_rows<<<M, 256, 0, stream>>>(hbuf, gamma, beta, out_ln);
}